// Round 2
// baseline (24905.429 us; speedup 1.0000x reference)
//
#include <hip/hip_runtime.h>
#include <math.h>

#define H 128
#define TB 32
#define TENC 20
#define TDEC 25

// ws layout (float offsets)
#define OFF_E0IH 0
#define OFF_E0HH (OFF_E0IH + 7*512)        // 3584
#define OFF_E1IH (OFF_E0HH + 128*512)      // 69120
#define OFF_E1HH (OFF_E1IH + 128*512)      // 134656
#define OFF_D0IH (OFF_E1HH + 128*512)      // 200192
#define OFF_D0HH (OFF_D0IH + 2*512)        // 201216
#define OFF_D1IH (OFF_D0HH + 128*512)      // 266752
#define OFF_D1HH (OFF_D1IH + 128*512)      // 332288
#define OFF_BE0  (OFF_D1HH + 128*512)      // 397824
#define OFF_BE1  (OFF_BE0 + 512)
#define OFF_BD0  (OFF_BE1 + 512)
#define OFF_BD1  (OFF_BD0 + 512)
#define WS_FLOATS (OFF_BD1 + 512)          // 399872 floats = 1.6 MB

__global__ void prep_kernel(
    const float* __restrict__ e0ih, const float* __restrict__ e0hh,
    const float* __restrict__ e1ih, const float* __restrict__ e1hh,
    const float* __restrict__ d0ih, const float* __restrict__ d0hh,
    const float* __restrict__ d1ih, const float* __restrict__ d1hh,
    const float* __restrict__ be0i, const float* __restrict__ be0h,
    const float* __restrict__ be1i, const float* __restrict__ be1h,
    const float* __restrict__ bd0i, const float* __restrict__ bd0h,
    const float* __restrict__ bd1i, const float* __restrict__ bd1h,
    float* __restrict__ ws)
{
  int idx = blockIdx.x * blockDim.x + threadIdx.x;
  if (idx >= WS_FLOATS) return;
  const float* in; int K; int off; int n;
  if (idx < 3584)        { in=e0ih; K=7;   off=OFF_E0IH; n=idx; }
  else if (idx < 69120)  { in=e0hh; K=128; off=OFF_E0HH; n=idx-3584; }
  else if (idx < 134656) { in=e1ih; K=128; off=OFF_E1IH; n=idx-69120; }
  else if (idx < 200192) { in=e1hh; K=128; off=OFF_E1HH; n=idx-134656; }
  else if (idx < 201216) { in=d0ih; K=2;   off=OFF_D0IH; n=idx-200192; }
  else if (idx < 266752) { in=d0hh; K=128; off=OFF_D0HH; n=idx-201216; }
  else if (idx < 332288) { in=d1ih; K=128; off=OFF_D1IH; n=idx-266752; }
  else if (idx < 397824) { in=d1hh; K=128; off=OFF_D1HH; n=idx-332288; }
  else {
    int b = idx - 397824;
    int which = b >> 9, r = b & 511;
    float v;
    if      (which==0) v = be0i[r]+be0h[r];
    else if (which==1) v = be1i[r]+be1h[r];
    else if (which==2) v = bd0i[r]+bd0h[r];
    else               v = bd1i[r]+bd1h[r];
    ws[397824 + b] = v;
    return;
  }
  // in is (512, K) row-major; write transposed [k][512]
  int j = n / K, k = n - j*K;
  ws[off + k*512 + j] = in[n];
}

__device__ __forceinline__ float sigm(float x) { return 1.0f/(1.0f + __expf(-x)); }
__device__ __forceinline__ float tanh_fast(float x) {
  x = fminf(fmaxf(x, -15.0f), 15.0f);
  float e = __expf(2.0f*x);
  return (e-1.0f)/(e+1.0f);
}

// acc[2][4][4] over (2 gates, 4 hidden, 4 samples); WT is [D][512] k-major.
template<int D>
__device__ __forceinline__ void gemm2(float acc[2][4][4],
    const float* __restrict__ WT, const float* xin, int g0, int g1,
    int my_k, int my_s)
{
  auto body = [&](int k) {
    const float* wr = WT + k*512;
    float4 wa = *(const float4*)(wr + g0*128 + my_k);
    float4 wb = *(const float4*)(wr + g1*128 + my_k);
    float4 xv = *(const float4*)(xin + k*TB + my_s);
    float hv[4]  = {xv.x,xv.y,xv.z,xv.w};
    float wav[4] = {wa.x,wa.y,wa.z,wa.w};
    float wbv[4] = {wb.x,wb.y,wb.z,wb.w};
    #pragma unroll
    for (int gi=0; gi<4; ++gi)
      #pragma unroll
      for (int s=0; s<4; ++s) {
        acc[0][gi][s] = fmaf(wav[gi], hv[s], acc[0][gi][s]);
        acc[1][gi][s] = fmaf(wbv[gi], hv[s], acc[1][gi][s]);
      }
  };
  if constexpr (D >= 16) {
    #pragma unroll 4
    for (int k=0; k<D; ++k) body(k);
  } else {
    #pragma unroll
    for (int k=0; k<D; ++k) body(k);
  }
}

// One LSTM layer step for this block's 32-sample tile.
// Two passes: pass A computes gates i,g ; pass B computes f,o (register pressure).
template<int D>
__device__ __forceinline__ void layer_step(
    const float* __restrict__ wtih, const float* __restrict__ wthh,
    const float* __restrict__ bias, const float* xin,
    float* hbuf, float cC[4][4], int my_k, int my_s)
{
  float accA[2][4][4];
  {
    float4 b0 = *(const float4*)(bias + 0*128 + my_k);
    float4 b2 = *(const float4*)(bias + 2*128 + my_k);
    float b0v[4]={b0.x,b0.y,b0.z,b0.w}, b2v[4]={b2.x,b2.y,b2.z,b2.w};
    #pragma unroll
    for (int gi=0; gi<4; ++gi)
      #pragma unroll
      for (int s=0; s<4; ++s) { accA[0][gi][s]=b0v[gi]; accA[1][gi][s]=b2v[gi]; }
  }
  gemm2<D>(accA, wtih, xin,  0, 2, my_k, my_s);
  gemm2<H>(accA, wthh, hbuf, 0, 2, my_k, my_s);
  float tmp[4][4];
  #pragma unroll
  for (int gi=0; gi<4; ++gi)
    #pragma unroll
    for (int s=0; s<4; ++s)
      tmp[gi][s] = sigm(accA[0][gi][s]) * tanh_fast(accA[1][gi][s]);

  float accB[2][4][4];
  {
    float4 b1 = *(const float4*)(bias + 1*128 + my_k);
    float4 b3 = *(const float4*)(bias + 3*128 + my_k);
    float b1v[4]={b1.x,b1.y,b1.z,b1.w}, b3v[4]={b3.x,b3.y,b3.z,b3.w};
    #pragma unroll
    for (int gi=0; gi<4; ++gi)
      #pragma unroll
      for (int s=0; s<4; ++s) { accB[0][gi][s]=b1v[gi]; accB[1][gi][s]=b3v[gi]; }
  }
  gemm2<D>(accB, wtih, xin,  1, 3, my_k, my_s);
  gemm2<H>(accB, wthh, hbuf, 1, 3, my_k, my_s);

  __syncthreads();   // all reads of hbuf complete before overwrite
  #pragma unroll
  for (int gi=0; gi<4; ++gi) {
    float4 hw;
    float hv[4];
    #pragma unroll
    for (int s=0; s<4; ++s) {
      float c = sigm(accB[0][gi][s]) * cC[gi][s] + tmp[gi][s];
      cC[gi][s] = c;
      hv[s] = sigm(accB[1][gi][s]) * tanh_fast(c);
    }
    hw.x=hv[0]; hw.y=hv[1]; hw.z=hv[2]; hw.w=hv[3];
    *(float4*)&hbuf[(my_k+gi)*TB + my_s] = hw;
  }
  __syncthreads();
}

__global__ __launch_bounds__(256, 4) void lstm_main(
    const float* __restrict__ target, const float* __restrict__ ws,
    const float* __restrict__ outW, const float* __restrict__ outB,
    float* __restrict__ out)
{
  __shared__ float h0s[H*TB];   // [k][s]
  __shared__ float h1s[H*TB];   // [k][s]
  __shared__ float xs[7*TB];    // [d][s]; decoder: rows 0-1 = x, rows 2-5 = proj partials

  const int tid = threadIdx.x;
  const int sg = tid & 7, kg = tid >> 3;
  const int my_s = sg*4, my_k = kg*4;
  const long sbase = (long)blockIdx.x * TB;

  float c0[4][4], c1[4][4];
  #pragma unroll
  for (int a=0; a<4; ++a)
    #pragma unroll
    for (int b=0; b<4; ++b) { c0[a][b]=0.f; c1[a][b]=0.f; }

  for (int i=tid; i<H*TB; i+=256) { h0s[i]=0.f; h1s[i]=0.f; }
  __syncthreads();

  const float* WT_e0ih = ws + OFF_E0IH;
  const float* WT_e0hh = ws + OFF_E0HH;
  const float* WT_e1ih = ws + OFF_E1IH;
  const float* WT_e1hh = ws + OFF_E1HH;
  const float* WT_d0ih = ws + OFF_D0IH;
  const float* WT_d0hh = ws + OFF_D0HH;
  const float* WT_d1ih = ws + OFF_D1IH;
  const float* WT_d1hh = ws + OFF_D1HH;
  const float* B_e0 = ws + OFF_BE0;
  const float* B_e1 = ws + OFF_BE1;
  const float* B_d0 = ws + OFF_BD0;
  const float* B_d1 = ws + OFF_BD1;

  // ---------------- encoder ----------------
  for (int t=0; t<TENC; ++t) {
    if (tid < 7*TB) {
      int s = tid / 7, d = tid - s*7;
      xs[d*TB + s] = target[(sbase + s)*(TENC*7) + t*7 + d];
    }
    __syncthreads();
    layer_step<7>(WT_e0ih, WT_e0hh, B_e0, xs,  h0s, c0, my_k, my_s);
    layer_step<H>(WT_e1ih, WT_e1hh, B_e1, h0s, h1s, c1, my_k, my_s);
  }

  // ---------------- decoder ----------------
  if (tid < 2*TB) xs[tid] = 0.f;   // x0 = zeros(B,2)
  __syncthreads();
  const float ob0 = outB[0], ob1 = outB[1];

  for (int p=0; p<TDEC; ++p) {
    layer_step<2>(WT_d0ih, WT_d0hh, B_d0, xs,  h0s, c0, my_k, my_s);
    layer_step<H>(WT_d1ih, WT_d1hh, B_d1, h0s, h1s, c1, my_k, my_s);

    // projection: pred[s][o] = h1[:,s] . outW[o,:] + outB[o]
    if (tid < 4*TB) {
      int s = tid & (TB-1), oh = tid >> 5;   // oh = o + 2*half
      int o = oh & 1, half = oh >> 1;
      const float* wo = outW + o*128 + half*64;
      const float* hc = h1s + (half*64)*TB + s;
      float acc = 0.f;
      #pragma unroll 8
      for (int k=0; k<64; ++k) acc = fmaf(hc[k*TB], wo[k], acc);
      xs[(2 + oh)*TB + s] = acc;
    }
    __syncthreads();
    if (tid < 2*TB) {
      int s2 = tid & (TB-1), o2 = tid >> 5;
      float pred = xs[(2+o2)*TB + s2] + xs[(4+o2)*TB + s2] + (o2 ? ob1 : ob0);
      out[((sbase + s2)*TDEC + p)*2 + o2] = pred;
      xs[o2*TB + s2] = pred;               // x for next decoder step
    }
    __syncthreads();
  }
}

extern "C" void kernel_launch(void* const* d_in, const int* in_sizes, int n_in,
                              void* d_out, int out_size, void* d_ws, size_t ws_size,
                              hipStream_t stream)
{
  const float* target = (const float*)d_in[0];
  const float* e0ih=(const float*)d_in[4],  *e0hh=(const float*)d_in[5];
  const float* be0i=(const float*)d_in[6],  *be0h=(const float*)d_in[7];
  const float* e1ih=(const float*)d_in[8],  *e1hh=(const float*)d_in[9];
  const float* be1i=(const float*)d_in[10], *be1h=(const float*)d_in[11];
  const float* d0ih=(const float*)d_in[12], *d0hh=(const float*)d_in[13];
  const float* bd0i=(const float*)d_in[14], *bd0h=(const float*)d_in[15];
  const float* d1ih=(const float*)d_in[16], *d1hh=(const float*)d_in[17];
  const float* bd1i=(const float*)d_in[18], *bd1h=(const float*)d_in[19];
  const float* outW=(const float*)d_in[20], *outB=(const float*)d_in[21];
  float* ws  = (float*)d_ws;
  float* out = (float*)d_out;
  const int B = in_sizes[0] / (TENC*7);     // 65536

  hipLaunchKernelGGL(prep_kernel, dim3((WS_FLOATS+255)/256), dim3(256), 0, stream,
      e0ih,e0hh,e1ih,e1hh,d0ih,d0hh,d1ih,d1hh,
      be0i,be0h,be1i,be1h,bd0i,bd0h,bd1i,bd1h, ws);
  hipLaunchKernelGGL(lstm_main, dim3(B/TB), dim3(256), 0, stream,
      target, ws, outW, outB, out);
}

// Round 3
// 20450.928 us; speedup vs baseline: 1.2178x; 1.2178x over previous
//
#include <hip/hip_runtime.h>
#include <math.h>

#define H 128
#define TB 16
#define XSTR 17          // padded LDS row stride (floats)
#define TENC 20
#define TDEC 25

// ws layout (float offsets) — all weight blocks are [K][512] with the 512
// permuted as [kg(64)][q(8)], q = gate(2b)<<1 | half: values for hidden pair
// (2*kg, 2*kg+1) of gates i,f (first float4) and g,o (second float4).
#define OFF_E0IH 0
#define OFF_E0HH (OFF_E0IH + 7*512)        // 3584
#define OFF_E1IH (OFF_E0HH + 128*512)      // 69120
#define OFF_E1HH (OFF_E1IH + 128*512)      // 134656
#define OFF_D0IH (OFF_E1HH + 128*512)      // 200192
#define OFF_D0HH (OFF_D0IH + 2*512)        // 201216
#define OFF_D1IH (OFF_D0HH + 128*512)      // 266752
#define OFF_D1HH (OFF_D1IH + 128*512)      // 332288
#define OFF_BE0  (OFF_D1HH + 128*512)      // 397824
#define OFF_BE1  (OFF_BE0 + 512)
#define OFF_BD0  (OFF_BE1 + 512)
#define OFF_BD1  (OFF_BD0 + 512)
#define WS_FLOATS (OFF_BD1 + 512)          // 399872 floats = 1.6 MB

__global__ void prep_kernel(
    const float* __restrict__ e0ih, const float* __restrict__ e0hh,
    const float* __restrict__ e1ih, const float* __restrict__ e1hh,
    const float* __restrict__ d0ih, const float* __restrict__ d0hh,
    const float* __restrict__ d1ih, const float* __restrict__ d1hh,
    const float* __restrict__ be0i, const float* __restrict__ be0h,
    const float* __restrict__ be1i, const float* __restrict__ be1h,
    const float* __restrict__ bd0i, const float* __restrict__ bd0h,
    const float* __restrict__ bd1i, const float* __restrict__ bd1h,
    float* __restrict__ ws)
{
  int idx = blockIdx.x * blockDim.x + threadIdx.x;
  if (idx >= WS_FLOATS) return;
  const float* in; int K; int n;
  if (idx < 3584)        { in=e0ih; K=7;   n=idx-OFF_E0IH; }
  else if (idx < 69120)  { in=e0hh; K=128; n=idx-OFF_E0HH; }
  else if (idx < 134656) { in=e1ih; K=128; n=idx-OFF_E1IH; }
  else if (idx < 200192) { in=e1hh; K=128; n=idx-OFF_E1HH; }
  else if (idx < 201216) { in=d0ih; K=2;   n=idx-OFF_D0IH; }
  else if (idx < 266752) { in=d0hh; K=128; n=idx-OFF_D0HH; }
  else if (idx < 332288) { in=d1ih; K=128; n=idx-OFF_D1IH; }
  else if (idx < 397824) { in=d1hh; K=128; n=idx-OFF_D1HH; }
  else {
    int b = idx - OFF_BE0;
    int which = b >> 9, r = b & 511;
    int kg = r >> 3, q = r & 7;
    int row = (q>>1)*128 + 2*kg + (q&1);
    float v;
    if      (which==0) v = be0i[row]+be0h[row];
    else if (which==1) v = be1i[row]+be1h[row];
    else if (which==2) v = bd0i[row]+bd0h[row];
    else               v = bd1i[row]+bd1h[row];
    ws[idx] = v;
    return;
  }
  // in is (512, K) row-major, gate order i,f,g,o; write permuted k-major
  int k = n / 512, r = n - k*512;
  int kg = r >> 3, q = r & 7;
  int row = (q>>1)*128 + 2*kg + (q&1);
  ws[idx] = in[row*K + k];
}

__device__ __forceinline__ float sigm(float x) { return 1.0f/(1.0f + __expf(-x)); }
__device__ __forceinline__ float tanh_fast(float x) {
  x = fminf(fmaxf(x, -15.0f), 15.0f);
  float e = __expf(2.0f*x);
  return (e-1.0f)/(e+1.0f);
}

// acc[gate(4)][half(2)][sample(4)]; WT is [D][512] permuted; xin stride XSTR.
template<int D>
__device__ __forceinline__ void gemm1(float acc[4][2][4],
    const float* __restrict__ WT, const float* xin, int kg, int my_s)
{
  auto body = [&](int k) {
    float4 wA = *(const float4*)(WT + k*512 + kg*8);      // i0,i1,f0,f1
    float4 wB = *(const float4*)(WT + k*512 + kg*8 + 4);  // g0,g1,o0,o1
    const float* xr = xin + k*XSTR + my_s;
    float x0 = xr[0], x1 = xr[1], x2 = xr[2], x3 = xr[3];
    float xv[4] = {x0,x1,x2,x3};
    #pragma unroll
    for (int s=0; s<4; ++s) {
      acc[0][0][s] = fmaf(wA.x, xv[s], acc[0][0][s]);
      acc[0][1][s] = fmaf(wA.y, xv[s], acc[0][1][s]);
      acc[1][0][s] = fmaf(wA.z, xv[s], acc[1][0][s]);
      acc[1][1][s] = fmaf(wA.w, xv[s], acc[1][1][s]);
      acc[2][0][s] = fmaf(wB.x, xv[s], acc[2][0][s]);
      acc[2][1][s] = fmaf(wB.y, xv[s], acc[2][1][s]);
      acc[3][0][s] = fmaf(wB.z, xv[s], acc[3][0][s]);
      acc[3][1][s] = fmaf(wB.w, xv[s], acc[3][1][s]);
    }
  };
  if constexpr (D >= 16) {
    #pragma unroll 8
    for (int k=0; k<D; ++k) body(k);
  } else {
    #pragma unroll
    for (int k=0; k<D; ++k) body(k);
  }
}

// One LSTM layer step for this block's 16-sample tile. Single pass, all gates.
template<int D>
__device__ __forceinline__ void layer_step(
    const float* __restrict__ wtih, const float* __restrict__ wthh,
    const float* __restrict__ bias, const float* xin,
    float* hbuf, float cC[2][4], int kg, int my_s)
{
  float acc[4][2][4];
  {
    float4 bA = *(const float4*)(bias + kg*8);      // i0,i1,f0,f1
    float4 bB = *(const float4*)(bias + kg*8 + 4);  // g0,g1,o0,o1
    #pragma unroll
    for (int s=0; s<4; ++s) {
      acc[0][0][s]=bA.x; acc[0][1][s]=bA.y;
      acc[1][0][s]=bA.z; acc[1][1][s]=bA.w;
      acc[2][0][s]=bB.x; acc[2][1][s]=bB.y;
      acc[3][0][s]=bB.z; acc[3][1][s]=bB.w;
    }
  }
  gemm1<D>(acc, wtih, xin,  kg, my_s);
  gemm1<H>(acc, wthh, hbuf, kg, my_s);

  __syncthreads();   // all reads of hbuf complete before overwrite
  #pragma unroll
  for (int h=0; h<2; ++h)
    #pragma unroll
    for (int s=0; s<4; ++s) {
      float iv = sigm(acc[0][h][s]);
      float fv = sigm(acc[1][h][s]);
      float gv = tanh_fast(acc[2][h][s]);
      float ov = sigm(acc[3][h][s]);
      float c  = fv * cC[h][s] + iv * gv;
      cC[h][s] = c;
      hbuf[(2*kg+h)*XSTR + my_s + s] = ov * tanh_fast(c);
    }
  __syncthreads();
}

__global__ __launch_bounds__(256, 4) void lstm_main(
    const float* __restrict__ target, const float* __restrict__ ws,
    const float* __restrict__ outW, const float* __restrict__ outB,
    float* __restrict__ out)
{
  __shared__ float h0s[H*XSTR];   // 8704 B
  __shared__ float h1s[H*XSTR];   // 8704 B
  __shared__ float xs[7*XSTR];    // enc inputs; dec: rows 0-1 = x feedback
  __shared__ float ps[8*TB];      // projection partials [oh][s]

  const int tid = threadIdx.x;
  const int kg = tid & 63;        // hidden-pair index 0..63
  const int sg = tid >> 6;        // sample group 0..3
  const int my_s = sg*4;
  const long sbase = (long)blockIdx.x * TB;

  float c0[2][4], c1[2][4];
  #pragma unroll
  for (int a=0; a<2; ++a)
    #pragma unroll
    for (int b=0; b<4; ++b) { c0[a][b]=0.f; c1[a][b]=0.f; }

  for (int i=tid; i<H*XSTR; i+=256) { h0s[i]=0.f; h1s[i]=0.f; }
  __syncthreads();

  const float* WT_e0ih = ws + OFF_E0IH;
  const float* WT_e0hh = ws + OFF_E0HH;
  const float* WT_e1ih = ws + OFF_E1IH;
  const float* WT_e1hh = ws + OFF_E1HH;
  const float* WT_d0ih = ws + OFF_D0IH;
  const float* WT_d0hh = ws + OFF_D0HH;
  const float* WT_d1ih = ws + OFF_D1IH;
  const float* WT_d1hh = ws + OFF_D1HH;
  const float* B_e0 = ws + OFF_BE0;
  const float* B_e1 = ws + OFF_BE1;
  const float* B_d0 = ws + OFF_BD0;
  const float* B_d1 = ws + OFF_BD1;

  // ---------------- encoder ----------------
  for (int t=0; t<TENC; ++t) {
    if (tid < 7*TB) {
      int s = tid / 7, d = tid - s*7;
      xs[d*XSTR + s] = target[(sbase + s)*(TENC*7) + t*7 + d];
    }
    __syncthreads();
    layer_step<7>(WT_e0ih, WT_e0hh, B_e0, xs,  h0s, c0, kg, my_s);
    layer_step<H>(WT_e1ih, WT_e1hh, B_e1, h0s, h1s, c1, kg, my_s);
  }

  // ---------------- decoder ----------------
  if (tid < 2*TB) {
    int o = tid >> 4, s = tid & 15;
    xs[o*XSTR + s] = 0.f;          // x0 = zeros(B,2)
  }
  __syncthreads();
  const float ob0 = outB[0], ob1 = outB[1];

  for (int p=0; p<TDEC; ++p) {
    layer_step<2>(WT_d0ih, WT_d0hh, B_d0, xs,  h0s, c0, kg, my_s);
    layer_step<H>(WT_d1ih, WT_d1hh, B_d1, h0s, h1s, c1, kg, my_s);

    // projection: pred[s][o] = h1[:,s] . outW[o,:] + outB[o]
    if (tid < 8*TB) {
      int s = tid & 15, oh = tid >> 4;       // oh = quarter*2 + o
      int o = oh & 1, quarter = oh >> 1;
      const float* wo = outW + o*128 + quarter*32;
      const float* hc = h1s + (quarter*32)*XSTR + s;
      float acc = 0.f;
      #pragma unroll 8
      for (int k=0; k<32; ++k) acc = fmaf(hc[k*XSTR], wo[k], acc);
      ps[oh*TB + s] = acc;
    }
    __syncthreads();
    if (tid < 2*TB) {
      int o = tid >> 4, s = tid & 15;
      float pred = ps[(0*2+o)*TB + s] + ps[(1*2+o)*TB + s]
                 + ps[(2*2+o)*TB + s] + ps[(3*2+o)*TB + s]
                 + (o ? ob1 : ob0);
      out[((sbase + s)*TDEC + p)*2 + o] = pred;
      xs[o*XSTR + s] = pred;               // x for next decoder step
    }
    __syncthreads();
  }
}

extern "C" void kernel_launch(void* const* d_in, const int* in_sizes, int n_in,
                              void* d_out, int out_size, void* d_ws, size_t ws_size,
                              hipStream_t stream)
{
  const float* target = (const float*)d_in[0];
  const float* e0ih=(const float*)d_in[4],  *e0hh=(const float*)d_in[5];
  const float* be0i=(const float*)d_in[6],  *be0h=(const float*)d_in[7];
  const float* e1ih=(const float*)d_in[8],  *e1hh=(const float*)d_in[9];
  const float* be1i=(const float*)d_in[10], *be1h=(const float*)d_in[11];
  const float* d0ih=(const float*)d_in[12], *d0hh=(const float*)d_in[13];
  const float* bd0i=(const float*)d_in[14], *bd0h=(const float*)d_in[15];
  const float* d1ih=(const float*)d_in[16], *d1hh=(const float*)d_in[17];
  const float* bd1i=(const float*)d_in[18], *bd1h=(const float*)d_in[19];
  const float* outW=(const float*)d_in[20], *outB=(const float*)d_in[21];
  float* ws  = (float*)d_ws;
  float* out = (float*)d_out;
  const int B = in_sizes[0] / (TENC*7);     // 65536

  hipLaunchKernelGGL(prep_kernel, dim3((WS_FLOATS+255)/256), dim3(256), 0, stream,
      e0ih,e0hh,e1ih,e1hh,d0ih,d0hh,d1ih,d1hh,
      be0i,be0h,be1i,be1h,bd0i,bd0h,bd1i,bd1h, ws);
  hipLaunchKernelGGL(lstm_main, dim3(B/TB), dim3(256), 0, stream,
      target, ws, outW, outB, out);
}